// Round 2
// baseline (291.632 us; speedup 1.0000x reference)
//
#include <hip/hip_runtime.h>
#include <hip/hip_cooperative_groups.h>
namespace cg = cooperative_groups;

#define HH 192
#define WW 192
#define HW 36864          // 192*192
#define BB 64
#define NPIX 2359296      // 64*192*192
#define NCH 48            // float4 chunks per row
#define LDST 196          // padded LDS row stride (floats)
#define TPB 768           // 48 chunks x 16 row-groups
#define WR 64             // window rows in LDS
#define SPANS 5
#define SPAN_ITERS 7

// ---------- conv kernels: 1 thread per float4 output chunk, vectorized ----------
__device__ __forceinline__ float4 conv3x3_chunk(const float* __restrict__ img,
                                                int y, int ch, const float* __restrict__ w9,
                                                float bias) {
  float4 acc = make_float4(bias, bias, bias, bias);
  int x0 = ch * 4;
#pragma unroll
  for (int dy = -1; dy <= 1; ++dy) {
    int yy = y + dy;
    if (yy < 0 || yy >= HH) continue;
    const float* row = img + yy * WW + x0;
    float4 v = *reinterpret_cast<const float4*>(row);
    float l = (ch > 0) ? row[-1] : 0.f;
    float r = (ch < NCH - 1) ? row[4] : 0.f;
    float wa = w9[(dy + 1) * 3 + 0];
    float wb = w9[(dy + 1) * 3 + 1];
    float wc = w9[(dy + 1) * 3 + 2];
    acc.x += wa * l   + wb * v.x + wc * v.y;
    acc.y += wa * v.x + wb * v.y + wc * v.z;
    acc.z += wa * v.y + wb * v.z + wc * v.w;
    acc.w += wa * v.z + wb * v.w + wc * r;
  }
  return acc;
}

// h = relu(conv3x3(grid)+hb); grid = X channel 0 (per-image stride 2*HW)
__global__ __launch_bounds__(256) void k_conv_h(const float* __restrict__ X,
                                                const float* __restrict__ w9,
                                                const float* __restrict__ b1,
                                                float* __restrict__ h) {
  int idx = blockIdx.x * 256 + threadIdx.x;
  if (idx >= NPIX / 4) return;
  int b = idx / (HW / 4);
  int rem = idx - b * (HW / 4);
  int y = rem / NCH;
  int ch = rem - y * NCH;
  float4 acc = conv3x3_chunk(X + (size_t)b * (2 * HW), y, ch, w9, b1[0]);
  acc.x = fmaxf(acc.x, 0.f); acc.y = fmaxf(acc.y, 0.f);
  acc.z = fmaxf(acc.z, 0.f); acc.w = fmaxf(acc.w, 0.f);
  *reinterpret_cast<float4*>(h + (size_t)b * HW + y * WW + ch * 4) = acc;
}

// p = sigmoid(conv3x3(h)+pb)
__global__ __launch_bounds__(256) void k_conv_p(const float* __restrict__ h,
                                                const float* __restrict__ w9,
                                                const float* __restrict__ b1,
                                                float* __restrict__ p_out) {
  int idx = blockIdx.x * 256 + threadIdx.x;
  if (idx >= NPIX / 4) return;
  int b = idx / (HW / 4);
  int rem = idx - b * (HW / 4);
  int y = rem / NCH;
  int ch = rem - y * NCH;
  float4 acc = conv3x3_chunk(h + (size_t)b * HW, y, ch, w9, b1[0]);
  acc.x = 1.f / (1.f + __expf(-acc.x));
  acc.y = 1.f / (1.f + __expf(-acc.y));
  acc.z = 1.f / (1.f + __expf(-acc.z));
  acc.w = 1.f / (1.f + __expf(-acc.w));
  *reinterpret_cast<float4*>(p_out + (size_t)b * HW + y * WW + ch * 4) = acc;
}

// ---------- persistent cooperative kernel: all 35 iterations ----------
// 256 blocks (1/CU): block (b, s) owns clean rows [s*48, s*48+48) of image b.
// LDS window: 64 rows, w in [0,64) <-> gy = s*48 - 8 + w (8-row halo each side).
// Every 7 iters: write own top/bottom 8 clean rows to halo buf, grid.sync(),
// read neighbors' 8-row halos. Ping-pong bufs => one sync per boundary is safe.
__global__ __launch_bounds__(TPB) void k_iter(const float* __restrict__ p_glob,
                                              const float* __restrict__ X,
                                              float* __restrict__ v_out,
                                              float* __restrict__ hbufA,
                                              float* __restrict__ hbufB) {
  __shared__ __align__(16) float vs[WR * LDST];
  cg::grid_group grid = cg::this_grid();

  int blk = blockIdx.x;
  int b = blk >> 2;
  int s = blk & 3;
  int y0 = s * 48;
  int gy0 = y0 - 8;            // global row of window row 0

  int tid = threadIdx.x;
  int ch = tid % NCH;
  int g = tid / NCH;           // 0..15
  int yb = g * 4;              // base window row of this thread
  int ch4 = ch * 4;

  const float* gimg = X + (size_t)b * (2 * HW) + HW;   // goal channel
  const float* pimg = p_glob + (size_t)b * HW;

  // ---- pinned p, c registers + v0 = goal-1 into LDS ----
  float4 pr[4], cr[4];
#pragma unroll
  for (int i = 0; i < 4; ++i) {
    int gy = gy0 + yb + i;
    if (gy >= 0 && gy < HH) {
      float4 g4 = *reinterpret_cast<const float4*>(gimg + gy * WW + ch4);
      float4 p4 = *reinterpret_cast<const float4*>(pimg + gy * WW + ch4);
      pr[i] = p4;
      cr[i].x = (g4.x - 1.f) * (1.f - p4.x);
      cr[i].y = (g4.y - 1.f) * (1.f - p4.y);
      cr[i].z = (g4.z - 1.f) * (1.f - p4.z);
      cr[i].w = (g4.w - 1.f) * (1.f - p4.w);
      float4 v0 = make_float4(g4.x - 1.f, g4.y - 1.f, g4.z - 1.f, g4.w - 1.f);
      *reinterpret_cast<float4*>(&vs[(yb + i) * LDST + ch4]) = v0;
    } else {
      pr[i] = make_float4(0.f, 0.f, 0.f, 0.f);
      cr[i] = make_float4(0.f, 0.f, 0.f, 0.f);
      *reinterpret_cast<float4*>(&vs[(yb + i) * LDST + ch4]) =
          make_float4(-1.f, -1.f, -1.f, -1.f);
    }
  }

  int ilw0 = (ch > 0) ? (ch4 - 1) : 0;  // left scalar (value overridden at ch==0)
  int irx0 = ch4 + 4;                   // right scalar (pad keeps in-bounds; overridden at ch==47)

  for (int span = 0; span < SPANS; ++span) {
    __syncthreads();
#pragma unroll 1
    for (int it = 0; it < SPAN_ITERS; ++it) {
      float4 nv[4];
      int gyw0 = gy0 + yb;
      int ym1 = (yb == 0 || gyw0 <= 0) ? yb : yb - 1;  // clamp at window AND image top
      float4 o_prev = *reinterpret_cast<const float4*>(&vs[ym1 * LDST + ch4]);
      float4 o_cur  = *reinterpret_cast<const float4*>(&vs[yb * LDST + ch4]);
      float lw_prev = vs[ym1 * LDST + ilw0];
      float lw_cur  = vs[yb * LDST + ilw0];
      float rx_prev = vs[ym1 * LDST + irx0];
      float rx_cur  = vs[yb * LDST + irx0];

#pragma unroll
      for (int i = 0; i < 4; ++i) {
        int y = yb + i;
        int gy = gy0 + y;
        int yp1 = (y == WR - 1 || gy >= HH - 1) ? y : y + 1;  // clamp window AND image bottom
        float4 o_next = *reinterpret_cast<const float4*>(&vs[yp1 * LDST + ch4]);
        float lw_next = vs[yp1 * LDST + ilw0];
        float rx_next = vs[yp1 * LDST + irx0];

        float4 vm;
        vm.x = fmaxf(fmaxf(o_prev.x, o_cur.x), o_next.x);
        vm.y = fmaxf(fmaxf(o_prev.y, o_cur.y), o_next.y);
        vm.z = fmaxf(fmaxf(o_prev.z, o_cur.z), o_next.z);
        vm.w = fmaxf(fmaxf(o_prev.w, o_cur.w), o_next.w);
        float lwm = fmaxf(fmaxf(lw_prev, lw_cur), lw_next);
        float rxm = fmaxf(fmaxf(rx_prev, rx_cur), rx_next);
        if (ch == 0) lwm = vm.x;
        if (ch == NCH - 1) rxm = vm.w;

        float4 hm;
        hm.x = fmaxf(lwm, fmaxf(vm.x, vm.y));
        hm.y = fmaxf(vm.x, fmaxf(vm.y, vm.z));
        hm.z = fmaxf(vm.y, fmaxf(vm.z, vm.w));
        hm.w = fmaxf(vm.z, fmaxf(vm.w, rxm));

        nv[i].x = fmaxf(o_cur.x, fmaf(pr[i].x, hm.x, cr[i].x));
        nv[i].y = fmaxf(o_cur.y, fmaf(pr[i].y, hm.y, cr[i].y));
        nv[i].z = fmaxf(o_cur.z, fmaf(pr[i].z, hm.z, cr[i].z));
        nv[i].w = fmaxf(o_cur.w, fmaf(pr[i].w, hm.w, cr[i].w));

        o_prev = o_cur; o_cur = o_next;
        lw_prev = lw_cur; lw_cur = lw_next;
        rx_prev = rx_cur; rx_cur = rx_next;
      }
      __syncthreads();
#pragma unroll
      for (int i = 0; i < 4; ++i)
        *reinterpret_cast<float4*>(&vs[(yb + i) * LDST + ch4]) = nv[i];
      __syncthreads();
    }

    if (span < SPANS - 1) {
      float* buf = (span & 1) ? hbufB : hbufA;
      // write own top (w 8..15) and bottom (w 48..55) clean rows: 16 rows * 48 ch = 768 = TPB
      {
        int half = tid / 384;              // 0 = top, 1 = bottom
        int rr = (tid - half * 384) / NCH; // 0..7
        int cc = tid % NCH;
        int w = half ? (48 + rr) : (8 + rr);
        float4 val = *reinterpret_cast<const float4*>(&vs[w * LDST + cc * 4]);
        size_t off = ((((size_t)blk) * 2 + half) * 8 + rr) * WW + cc * 4;
        *reinterpret_cast<float4*>(buf + off) = val;
      }
      grid.sync();
      // read neighbor halos: w 0..7 <- (blk-1, bottom); w 56..63 <- (blk+1, top)
      {
        int half = tid / 384;
        int rr = (tid - half * 384) / NCH;
        int cc = tid % NCH;
        if (half == 0) {
          if (s > 0) {
            size_t off = ((((size_t)(blk - 1)) * 2 + 1) * 8 + rr) * WW + cc * 4;
            *reinterpret_cast<float4*>(&vs[rr * LDST + cc * 4]) =
                *reinterpret_cast<const float4*>(buf + off);
          }
        } else {
          if (s < 3) {
            size_t off = ((((size_t)(blk + 1)) * 2 + 0) * 8 + rr) * WW + cc * 4;
            *reinterpret_cast<float4*>(&vs[(56 + rr) * LDST + cc * 4]) =
                *reinterpret_cast<const float4*>(buf + off);
          }
        }
      }
      // visibility of these LDS writes: __syncthreads at top of next span
    }
  }

  // ---- store the 48 clean rows (w 8..55) ----
  __syncthreads();
  float* vout = v_out + (size_t)b * HW;
  for (int t = tid; t < 48 * NCH; t += TPB) {
    int r = t / NCH, c2 = t - r * NCH;
    float4 val = *reinterpret_cast<const float4*>(&vs[(8 + r) * LDST + c2 * 4]);
    *reinterpret_cast<float4*>(vout + (y0 + r) * WW + c2 * 4) = val;
  }
}

// ---------------- launch ----------------
extern "C" void kernel_launch(void* const* d_in, const int* in_sizes, int n_in,
                              void* d_out, int out_size, void* d_ws, size_t ws_size,
                              hipStream_t stream) {
  const float* X = (const float*)d_in[0];
  const float* hp_w = (const float*)d_in[1];
  const float* hp_b = (const float*)d_in[2];
  const float* p_w = (const float*)d_in[3];
  const float* p_b = (const float*)d_in[4];

  float* out = (float*)d_out;
  float* out_v = out;          // NPIX floats (final v)
  float* out_p = out + NPIX;   // NPIX floats (p)

  // h scratch lives in out_v (dead before k_iter's final write)
  float* h = out_v;
  // halo exchange ping-pong buffers in ws: each 64*4*2*8*192 = 786432 floats (3MB)
  float* hbufA = (float*)d_ws;
  float* hbufB = hbufA + (size_t)BB * 4 * 2 * 8 * WW;

  int nblk = (NPIX / 4 + 255) / 256;
  k_conv_h<<<nblk, 256, 0, stream>>>(X, hp_w, hp_b, h);
  k_conv_p<<<nblk, 256, 0, stream>>>(h, p_w, p_b, out_p);

  const float* p_c = out_p;
  void* args[] = { (void*)&p_c, (void*)&X, (void*)&out_v, (void*)&hbufA, (void*)&hbufB };
  hipLaunchCooperativeKernel((const void*)k_iter, dim3(BB * 4), dim3(TPB), args, 0, stream);
}

// Round 4
// 166.392 us; speedup vs baseline: 1.7527x; 1.7527x over previous
//
#include <hip/hip_runtime.h>

#define HH 192
#define WW 192
#define HW 36864          // 192*192
#define BB 64
#define NPIX 2359296      // 64*192*192
#define NCH 48            // float4 chunks per row
#define NEG (-1.0e30f)

// ---------- conv kernels (round-2 known-good): 1 thread per float4 chunk ----------
__device__ __forceinline__ float4 conv3x3_chunk(const float* __restrict__ img,
                                                int y, int ch, const float* __restrict__ w9,
                                                float bias) {
  float4 acc = make_float4(bias, bias, bias, bias);
  int x0 = ch * 4;
#pragma unroll
  for (int dy = -1; dy <= 1; ++dy) {
    int yy = y + dy;
    if (yy < 0 || yy >= HH) continue;
    const float* row = img + yy * WW + x0;
    float4 v = *reinterpret_cast<const float4*>(row);
    float l = (ch > 0) ? row[-1] : 0.f;
    float r = (ch < NCH - 1) ? row[4] : 0.f;
    float wa = w9[(dy + 1) * 3 + 0];
    float wb = w9[(dy + 1) * 3 + 1];
    float wc = w9[(dy + 1) * 3 + 2];
    acc.x += wa * l   + wb * v.x + wc * v.y;
    acc.y += wa * v.x + wb * v.y + wc * v.z;
    acc.z += wa * v.y + wb * v.z + wc * v.w;
    acc.w += wa * v.z + wb * v.w + wc * r;
  }
  return acc;
}

__global__ __launch_bounds__(256) void k_conv_h(const float* __restrict__ X,
                                                const float* __restrict__ w9,
                                                const float* __restrict__ b1,
                                                float* __restrict__ h) {
  int idx = blockIdx.x * 256 + threadIdx.x;
  if (idx >= NPIX / 4) return;
  int b = idx / (HW / 4);
  int rem = idx - b * (HW / 4);
  int y = rem / NCH;
  int ch = rem - y * NCH;
  float4 acc = conv3x3_chunk(X + (size_t)b * (2 * HW), y, ch, w9, b1[0]);
  acc.x = fmaxf(acc.x, 0.f); acc.y = fmaxf(acc.y, 0.f);
  acc.z = fmaxf(acc.z, 0.f); acc.w = fmaxf(acc.w, 0.f);
  *reinterpret_cast<float4*>(h + (size_t)b * HW + y * WW + ch * 4) = acc;
}

__global__ __launch_bounds__(256) void k_conv_p(const float* __restrict__ h,
                                                const float* __restrict__ w9,
                                                const float* __restrict__ b1,
                                                float* __restrict__ p_out) {
  int idx = blockIdx.x * 256 + threadIdx.x;
  if (idx >= NPIX / 4) return;
  int b = idx / (HW / 4);
  int rem = idx - b * (HW / 4);
  int y = rem / NCH;
  int ch = rem - y * NCH;
  float4 acc = conv3x3_chunk(h + (size_t)b * HW, y, ch, w9, b1[0]);
  acc.x = 1.f / (1.f + __expf(-acc.x));
  acc.y = 1.f / (1.f + __expf(-acc.y));
  acc.z = 1.f / (1.f + __expf(-acc.z));
  acc.w = 1.f / (1.f + __expf(-acc.w));
  *reinterpret_cast<float4*>(p_out + (size_t)b * HW + y * WW + ch * 4) = acc;
}

// ---------- register-resident span kernel: 7 value iterations, no LDS/barriers ----------
// 1024 waves (256 blocks x 4); wave owns a 64x64 tile (clean interior 48x48) of
// image b: lane (ly,lx) of the 8x8 lane grid holds an 8x8 pixel patch in VGPRs.
// Halos via __shfl. Loads window (v,p,goal) from global, runs 7 iters, writes the
// clean 48x48. Contamination from the window edge travels 7 px < 8-px halo.
template <int FIRST>
__global__ __launch_bounds__(256, 1) void k_span(const float* __restrict__ v_in,
                                                 const float* __restrict__ p_glob,
                                                 const float* __restrict__ X,
                                                 float* __restrict__ v_out) {
  int wid = blockIdx.x * 4 + (threadIdx.x >> 6);
  int lane = threadIdx.x & 63;
  int b = wid >> 4;
  int t = wid & 15;
  int ti = t >> 2, tj = t & 3;
  int ly = lane >> 3, lx = lane & 7;
  int py = ti * 48 - 8 + ly * 8;   // global row of patch row 0 (multiple of 8, may be <0/>=192)
  int px = tj * 48 - 8 + lx * 8;   // global col of patch col 0
  bool colok = (px >= 0 && px < WW);

  const float* gimg = X + (size_t)b * (2 * HW) + HW;  // goal channel
  const float* pimg = p_glob + (size_t)b * HW;
  const float* vimg = v_in + (size_t)b * HW;

  float v[8][8], p[8][8], c[8][8];
#pragma unroll
  for (int r = 0; r < 8; ++r) {
    int gy = py + r;
    if (colok && gy >= 0 && gy < HH) {
      float4 g0 = *(const float4*)(gimg + gy * WW + px);
      float4 g1 = *(const float4*)(gimg + gy * WW + px + 4);
      float4 p0 = *(const float4*)(pimg + gy * WW + px);
      float4 p1 = *(const float4*)(pimg + gy * WW + px + 4);
      float gg[8] = {g0.x, g0.y, g0.z, g0.w, g1.x, g1.y, g1.z, g1.w};
      float pp[8] = {p0.x, p0.y, p0.z, p0.w, p1.x, p1.y, p1.z, p1.w};
#pragma unroll
      for (int j = 0; j < 8; ++j) {
        p[r][j] = pp[j];
        c[r][j] = (gg[j] - 1.f) * (1.f - pp[j]);
      }
      if (FIRST) {
#pragma unroll
        for (int j = 0; j < 8; ++j) v[r][j] = gg[j] - 1.f;   // v0 = goal-1
      } else {
        float4 v0 = *(const float4*)(vimg + gy * WW + px);
        float4 v1 = *(const float4*)(vimg + gy * WW + px + 4);
        v[r][0] = v0.x; v[r][1] = v0.y; v[r][2] = v0.z; v[r][3] = v0.w;
        v[r][4] = v1.x; v[r][5] = v1.y; v[r][6] = v1.z; v[r][7] = v1.w;
      }
    } else {
#pragma unroll
      for (int j = 0; j < 8; ++j) { v[r][j] = NEG; p[r][j] = 0.f; c[r][j] = NEG; }
    }
  }

  int lup = (lane - 8) & 63, ldn = (lane + 8) & 63;
  int llt = (lane - 1) & 63, lrt = (lane + 1) & 63;

#pragma unroll 1
  for (int it = 0; it < 7; ++it) {
    // top/bottom halo rows from vertical lane neighbors (window edge -> -inf)
    float th[8], bh[8];
#pragma unroll
    for (int j = 0; j < 8; ++j) { float s = __shfl(v[7][j], lup, 64); th[j] = (ly == 0) ? NEG : s; }
#pragma unroll
    for (int j = 0; j < 8; ++j) { float s = __shfl(v[0][j], ldn, 64); bh[j] = (ly == 7) ? NEG : s; }
    // vertical 3-max, fully materialized from old v
    float vm[8][8];
#pragma unroll
    for (int r = 0; r < 8; ++r) {
#pragma unroll
      for (int j = 0; j < 8; ++j) {
        float up = (r == 0) ? th[j] : v[r - 1][j];
        float dn = (r == 7) ? bh[j] : v[r + 1][j];
        vm[r][j] = fmaxf(fmaxf(up, dn), v[r][j]);
      }
    }
    // horizontal 3-max + update; edge columns via lateral shuffles
#pragma unroll
    for (int r = 0; r < 8; ++r) {
      float sl = __shfl(vm[r][7], llt, 64);
      float sr = __shfl(vm[r][0], lrt, 64);
      float lvm = (lx == 0) ? NEG : sl;
      float rvm = (lx == 7) ? NEG : sr;
      float hm0 = fmaxf(lvm, fmaxf(vm[r][0], vm[r][1]));
      float hm7 = fmaxf(vm[r][6], fmaxf(vm[r][7], rvm));
      v[r][0] = fmaxf(v[r][0], fmaf(p[r][0], hm0, c[r][0]));
#pragma unroll
      for (int j = 1; j < 7; ++j) {
        float hm = fmaxf(vm[r][j - 1], fmaxf(vm[r][j], vm[r][j + 1]));
        v[r][j] = fmaxf(v[r][j], fmaf(p[r][j], hm, c[r][j]));
      }
      v[r][7] = fmaxf(v[r][7], fmaf(p[r][7], hm7, c[r][7]));
    }
  }

  // write clean 48x48 (interior lanes only; coordinates always in-image)
  if (ly >= 1 && ly <= 6 && lx >= 1 && lx <= 6) {
    float* wimg = v_out + (size_t)b * HW;
#pragma unroll
    for (int r = 0; r < 8; ++r) {
      *(float4*)(wimg + (py + r) * WW + px) = make_float4(v[r][0], v[r][1], v[r][2], v[r][3]);
      *(float4*)(wimg + (py + r) * WW + px + 4) = make_float4(v[r][4], v[r][5], v[r][6], v[r][7]);
    }
  }
}

// ---------------- launch ----------------
extern "C" void kernel_launch(void* const* d_in, const int* in_sizes, int n_in,
                              void* d_out, int out_size, void* d_ws, size_t ws_size,
                              hipStream_t stream) {
  const float* X = (const float*)d_in[0];
  const float* hp_w = (const float*)d_in[1];
  const float* hp_b = (const float*)d_in[2];
  const float* p_w = (const float*)d_in[3];
  const float* p_b = (const float*)d_in[4];

  float* out = (float*)d_out;
  float* out_v = out;          // NPIX floats (final v)
  float* out_p = out + NPIX;   // NPIX floats (p)
  float* bufA = (float*)d_ws;  // NPIX floats ping buffer (>=9.4MB proven in round 1)

  // h staged in out_v: consumed by k_conv_p before span 0 overwrites out_v
  float* h = out_v;

  int nblk = (NPIX / 4 + 255) / 256;
  k_conv_h<<<nblk, 256, 0, stream>>>(X, hp_w, hp_b, h);
  k_conv_p<<<nblk, 256, 0, stream>>>(h, p_w, p_b, out_p);

  // spans: W = [out_v, bufA, out_v, bufA, out_v]; reader != writer each hop
  k_span<1><<<256, 256, 0, stream>>>(X /*unused*/, out_p, X, out_v);
  k_span<0><<<256, 256, 0, stream>>>(out_v, out_p, X, bufA);
  k_span<0><<<256, 256, 0, stream>>>(bufA, out_p, X, out_v);
  k_span<0><<<256, 256, 0, stream>>>(out_v, out_p, X, bufA);
  k_span<0><<<256, 256, 0, stream>>>(bufA, out_p, X, out_v);
}

// Round 5
// 160.849 us; speedup vs baseline: 1.8131x; 1.0345x over previous
//
#include <hip/hip_runtime.h>

#define HH 192
#define WW 192
#define HW 36864          // 192*192
#define BB 64
#define NPIX 2359296      // 64*192*192
#define NEG (-1.0e30f)

// ---------------- fused conv: p = sigmoid(conv(relu(conv(grid)+hb))+pb) ----------------
// One thread per float4 of p. h recomputed redundantly (18 values/thread) from a
// 5x8 grid patch — no h round-trip, one launch. Verified: gr covers rows y-2..y+2,
// cols x0-2..x0+5 zero-padded; h zero outside image (second conv 'same' zero-pad).
__global__ __launch_bounds__(256) void k_conv_fused(const float* __restrict__ X,
                                                    const float* __restrict__ hw9,
                                                    const float* __restrict__ hb,
                                                    const float* __restrict__ pw9,
                                                    const float* __restrict__ pb,
                                                    float* __restrict__ p_out) {
  int idx = blockIdx.x * 256 + threadIdx.x;
  if (idx >= NPIX / 4) return;
  int b = idx / (HW / 4);
  int rem = idx - b * (HW / 4);
  int y = rem / 48;
  int ch = rem - y * 48;
  int x0 = ch * 4;
  const float* g = X + (size_t)b * (2 * HW);  // grid = channel 0

  float gr[5][8];
#pragma unroll
  for (int ry = 0; ry < 5; ++ry) {
    int yy = y - 2 + ry;
    if (yy < 0 || yy >= HH) {
#pragma unroll
      for (int j = 0; j < 8; ++j) gr[ry][j] = 0.f;
    } else {
      const float* row = g + yy * WW;
      float4 a = (x0 >= 4) ? *(const float4*)(row + x0 - 4) : make_float4(0, 0, 0, 0);
      float4 m = *(const float4*)(row + x0);
      float4 cq = (x0 + 4 < WW) ? *(const float4*)(row + x0 + 4) : make_float4(0, 0, 0, 0);
      gr[ry][0] = a.z; gr[ry][1] = a.w;
      gr[ry][2] = m.x; gr[ry][3] = m.y; gr[ry][4] = m.z; gr[ry][5] = m.w;
      gr[ry][6] = cq.x; gr[ry][7] = cq.y;
    }
  }
  float hwv[9], pwv[9];
#pragma unroll
  for (int i = 0; i < 9; ++i) { hwv[i] = hw9[i]; pwv[i] = pw9[i]; }
  float hbv = hb[0], pbv = pb[0];

  float hr[3][6];
#pragma unroll
  for (int ry = 0; ry < 3; ++ry) {
    int yy = y - 1 + ry;
    bool rowok = (yy >= 0 && yy < HH);
#pragma unroll
    for (int j = 0; j < 6; ++j) {
      int xx = x0 - 1 + j;
      float acc = hbv;
#pragma unroll
      for (int di = 0; di < 3; ++di)
#pragma unroll
        for (int dj = 0; dj < 3; ++dj)
          acc = fmaf(gr[ry + di][j + dj], hwv[di * 3 + dj], acc);
      hr[ry][j] = (rowok && xx >= 0 && xx < WW) ? fmaxf(acc, 0.f) : 0.f;
    }
  }
  float o[4];
#pragma unroll
  for (int k = 0; k < 4; ++k) {
    float acc = pbv;
#pragma unroll
    for (int di = 0; di < 3; ++di)
#pragma unroll
      for (int dj = 0; dj < 3; ++dj)
        acc = fmaf(hr[di][k + dj], pwv[di * 3 + dj], acc);
    o[k] = 1.f / (1.f + __expf(-acc));
  }
  *(float4*)(p_out + (size_t)b * HW + y * WW + x0) = make_float4(o[0], o[1], o[2], o[3]);
}

// ---------- register-resident span kernel: 7 value iterations, batched loads ----------
// Identical tile math to round 4 (verified). Only change: all global loads issued
// in consumption-free unrolled loops (p, goal, v) so the compiler batches them
// into one in-flight group — one miss latency instead of 48, critical at
// 1 wave/SIMD on a poison-cold cache.
template <int FIRST>
__global__ __launch_bounds__(256, 1) void k_span(const float* __restrict__ v_in,
                                                 const float* __restrict__ p_glob,
                                                 const float* __restrict__ X,
                                                 float* __restrict__ v_out) {
  int wid = blockIdx.x * 4 + (threadIdx.x >> 6);
  int lane = threadIdx.x & 63;
  int b = wid >> 4;
  int t = wid & 15;
  int ti = t >> 2, tj = t & 3;
  int ly = lane >> 3, lx = lane & 7;
  int py = ti * 48 - 8 + ly * 8;
  int px = tj * 48 - 8 + lx * 8;
  bool colok = (px >= 0 && px < WW);

  const float* gimg = X + (size_t)b * (2 * HW) + HW;
  const float* pimg = p_glob + (size_t)b * HW;
  const float* vimg = v_in + (size_t)b * HW;

  float v[8][8], p[8][8], c[8][8];

  // ---- phase 1: pure loads, no consumption (compiler batches all in flight) ----
#pragma unroll
  for (int r = 0; r < 8; ++r) {
    int gy = py + r;
    if (colok && gy >= 0 && gy < HH) {
      *(float4*)&p[r][0] = *(const float4*)(pimg + gy * WW + px);
      *(float4*)&p[r][4] = *(const float4*)(pimg + gy * WW + px + 4);
    }
  }
#pragma unroll
  for (int r = 0; r < 8; ++r) {
    int gy = py + r;
    if (colok && gy >= 0 && gy < HH) {
      *(float4*)&c[r][0] = *(const float4*)(gimg + gy * WW + px);   // raw goal
      *(float4*)&c[r][4] = *(const float4*)(gimg + gy * WW + px + 4);
    }
  }
  if (!FIRST) {
#pragma unroll
    for (int r = 0; r < 8; ++r) {
      int gy = py + r;
      if (colok && gy >= 0 && gy < HH) {
        *(float4*)&v[r][0] = *(const float4*)(vimg + gy * WW + px);
        *(float4*)&v[r][4] = *(const float4*)(vimg + gy * WW + px + 4);
      }
    }
  }

  // ---- phase 2: combine ----
#pragma unroll
  for (int r = 0; r < 8; ++r) {
    int gy = py + r;
    if (colok && gy >= 0 && gy < HH) {
#pragma unroll
      for (int j = 0; j < 8; ++j) {
        float gg = c[r][j];
        if (FIRST) v[r][j] = gg - 1.f;
        c[r][j] = (gg - 1.f) * (1.f - p[r][j]);
      }
    } else {
#pragma unroll
      for (int j = 0; j < 8; ++j) { v[r][j] = NEG; p[r][j] = 0.f; c[r][j] = NEG; }
    }
  }

  int lup = (lane - 8) & 63, ldn = (lane + 8) & 63;
  int llt = (lane - 1) & 63, lrt = (lane + 1) & 63;

#pragma unroll 1
  for (int it = 0; it < 7; ++it) {
    float th[8], bh[8];
#pragma unroll
    for (int j = 0; j < 8; ++j) { float s = __shfl(v[7][j], lup, 64); th[j] = (ly == 0) ? NEG : s; }
#pragma unroll
    for (int j = 0; j < 8; ++j) { float s = __shfl(v[0][j], ldn, 64); bh[j] = (ly == 7) ? NEG : s; }
    float vm[8][8];
#pragma unroll
    for (int r = 0; r < 8; ++r) {
#pragma unroll
      for (int j = 0; j < 8; ++j) {
        float up = (r == 0) ? th[j] : v[r - 1][j];
        float dn = (r == 7) ? bh[j] : v[r + 1][j];
        vm[r][j] = fmaxf(fmaxf(up, dn), v[r][j]);
      }
    }
#pragma unroll
    for (int r = 0; r < 8; ++r) {
      float sl = __shfl(vm[r][7], llt, 64);
      float sr = __shfl(vm[r][0], lrt, 64);
      float lvm = (lx == 0) ? NEG : sl;
      float rvm = (lx == 7) ? NEG : sr;
      float hm0 = fmaxf(lvm, fmaxf(vm[r][0], vm[r][1]));
      float hm7 = fmaxf(vm[r][6], fmaxf(vm[r][7], rvm));
      v[r][0] = fmaxf(v[r][0], fmaf(p[r][0], hm0, c[r][0]));
#pragma unroll
      for (int j = 1; j < 7; ++j) {
        float hm = fmaxf(vm[r][j - 1], fmaxf(vm[r][j], vm[r][j + 1]));
        v[r][j] = fmaxf(v[r][j], fmaf(p[r][j], hm, c[r][j]));
      }
      v[r][7] = fmaxf(v[r][7], fmaf(p[r][7], hm7, c[r][7]));
    }
  }

  // ---- store clean 48x48 (interior lanes; coordinates always in-image) ----
  if (ly >= 1 && ly <= 6 && lx >= 1 && lx <= 6) {
    float* wimg = v_out + (size_t)b * HW;
#pragma unroll
    for (int r = 0; r < 8; ++r) {
      *(float4*)(wimg + (py + r) * WW + px) = make_float4(v[r][0], v[r][1], v[r][2], v[r][3]);
      *(float4*)(wimg + (py + r) * WW + px + 4) = make_float4(v[r][4], v[r][5], v[r][6], v[r][7]);
    }
  }
}

// ---------------- launch ----------------
extern "C" void kernel_launch(void* const* d_in, const int* in_sizes, int n_in,
                              void* d_out, int out_size, void* d_ws, size_t ws_size,
                              hipStream_t stream) {
  const float* X = (const float*)d_in[0];
  const float* hp_w = (const float*)d_in[1];
  const float* hp_b = (const float*)d_in[2];
  const float* p_w = (const float*)d_in[3];
  const float* p_b = (const float*)d_in[4];

  float* out = (float*)d_out;
  float* out_v = out;          // NPIX floats (final v)
  float* out_p = out + NPIX;   // NPIX floats (p)
  float* bufA = (float*)d_ws;  // NPIX floats ping buffer

  int nblk = (NPIX / 4 + 255) / 256;
  k_conv_fused<<<nblk, 256, 0, stream>>>(X, hp_w, hp_b, p_w, p_b, out_p);

  // spans: W = [out_v, bufA, out_v, bufA, out_v]; reader != writer each hop
  k_span<1><<<256, 256, 0, stream>>>(X /*unused*/, out_p, X, out_v);
  k_span<0><<<256, 256, 0, stream>>>(out_v, out_p, X, bufA);
  k_span<0><<<256, 256, 0, stream>>>(bufA, out_p, X, out_v);
  k_span<0><<<256, 256, 0, stream>>>(out_v, out_p, X, bufA);
  k_span<0><<<256, 256, 0, stream>>>(bufA, out_p, X, out_v);
}